// Round 4
// baseline (64.215 us; speedup 1.0000x reference)
//
#include <hip/hip_runtime.h>
#include <hip/hip_bf16.h>
#include <math.h>

#define KCURV  0.1f
#define KK     0.010000001f          // k*k
#define SQRT_K 0.31622776601683794f
#define TWO_SQRT_K 0.6324555320336759f
#define INV_SQRT_K 3.1622776601683795f
#define TD 64   // feature dim D
#define LDP 72  // LDS row stride in bf16 elems: 144 B -> 2-way max bank alias

typedef __bf16  bf16x8  __attribute__((ext_vector_type(8)));
typedef float   f32x4   __attribute__((ext_vector_type(4)));

__device__ __forceinline__ unsigned short f2bf(float f) {
    __hip_bfloat16 h = __float2bfloat16(f);
    return *(unsigned short*)&h;
}

// Single dispatch. 512 threads / 8 waves, 128 rows x 64 classes per block,
// 256 blocks = 1/CU.
//
// Phase 1 (all 512 threads): 8 threads/class x 8 elems; shfl_xor(1,2,4)
// finishes class reductions; bf16 fragments -> padded LDS ([64][72]).
// x loads + y2 + x->bf16 conversion issued BEFORE the barrier.
//
// Phase 2: SWAPPED MFMA operands — A = class fragment, B = x fragment.
// C/D layout (col=lane&15, row=quad*4+reg) then gives:
//   col = x-row (= m16, the row this lane loaded -> y2 is lane-local, no
//         shuffles), row = class (4 consecutive classes per lane)
// so each lane writes ONE float4 per t (4 total) instead of 16 scalar
// column-stride stores. C % 4 == 0 -> stores never straddle the tail.
__global__ __launch_bounds__(512) void fused_mlr_kernel(
    const float* __restrict__ x,
    const float* __restrict__ a_vals,
    const float* __restrict__ p_vals,
    float* __restrict__ out, int B, int C)
{
    __shared__ unsigned short Pl[64 * LDP];
    __shared__ unsigned short Al[64 * LDP];
    __shared__ float scal[4][64];          // x2, pa, an, sc

    const int tid  = threadIdx.x;
    const int w    = tid >> 6;             // 0..7
    const int lane = tid & 63;
    const int m16  = lane & 15;
    const int quad = lane >> 4;
    const int cb   = blockIdx.x * 64;
    const int rb   = blockIdx.y * 128;
    const int gr   = rb + 16 * w + m16;    // this lane's x row
    const int arow = gr < B ? gr : B - 1;

    // ---- class loads first (critical path: load -> prep -> LDS -> barrier)
    const int ci = tid >> 3;               // class in tile, 0..63
    const int o  = tid & 7;                // k-octet, 8 elems
    int c = cb + ci; if (c >= C) c = C - 1;       // tail clamp (store masked)
    const float* pr = p_vals + (size_t)c * TD + o * 8;
    const float* ar = a_vals + (size_t)c * TD + o * 8;
    float pv[8], av[8];
    *(float4*)&pv[0] = *(const float4*)pr;
    *(float4*)&pv[4] = *(const float4*)(pr + 4);
    *(float4*)&av[0] = *(const float4*)ar;
    *(float4*)&av[4] = *(const float4*)(ar + 4);

    // ---- x loads (independent of prep) -----------------------------------
    float xv[2][8];
    #pragma unroll
    for (int step = 0; step < 2; ++step) {
        const int ko = quad * 8 + step * 32;
        const float* xr = x + (size_t)arow * TD + ko;
        *(float4*)&xv[step][0] = *(const float4*)xr;
        *(float4*)&xv[step][4] = *(const float4*)(xr + 4);
    }

    // ---- phase 1: cooperative class prep into LDS ------------------------
    {
        float s_pp = 0.f, s_aa = 0.f, s_pa = 0.f;
        #pragma unroll
        for (int u = 0; u < 8; ++u) {
            s_pp = fmaf(pv[u], pv[u], s_pp);
            s_aa = fmaf(av[u], av[u], s_aa);
            s_pa = fmaf(pv[u], av[u], s_pa);
        }
        // 8 threads per class -> xor(1,2,4) completes the row sums
        s_pp += __shfl_xor(s_pp, 1, 64); s_aa += __shfl_xor(s_aa, 1, 64);
        s_pa += __shfl_xor(s_pa, 1, 64);
        s_pp += __shfl_xor(s_pp, 2, 64); s_aa += __shfl_xor(s_aa, 2, 64);
        s_pa += __shfl_xor(s_pa, 2, 64);
        s_pp += __shfl_xor(s_pp, 4, 64); s_aa += __shfl_xor(s_aa, 4, 64);
        s_pa += __shfl_xor(s_pa, 4, 64);

        float pn = sqrtf(s_pp); if (pn < 1e-15f) pn = 1e-15f;
        float arg = SQRT_K * pn;
        float e2 = __expf(2.0f * arg);
        float th = (e2 - 1.0f) * __builtin_amdgcn_rcpf(e2 + 1.0f);
        float factor = (arg > 1e-4f) ? th * __builtin_amdgcn_rcpf(arg)
                                     : 1.0f - 0.333333333f * arg * arg;
        float p2 = factor * factor * s_pp;      // ||p_poin||^2
        float ca = 1.0f + KCURV * p2;           // a_poin = ca * a
        float anorm = ca * sqrtf(s_aa); if (anorm < 1e-15f) anorm = 1e-15f;
        float lam = 2.0f * __builtin_amdgcn_rcpf(1.0f - KCURV * p2);
        if (o == 0) {
            scal[0][ci] = p2;
            scal[1][ci] = -factor * ca * s_pa;  // sum(mp * a_poin)
            scal[2][ci] = anorm;
            scal[3][ci] = lam * anorm * INV_SQRT_K;
        }
        union { unsigned short u[8]; bf16x8 v; } cp, da;
        #pragma unroll
        for (int u = 0; u < 8; ++u) {
            cp.u[u] = f2bf(-factor * pv[u]);
            da.u[u] = f2bf(ca * av[u]);
        }
        *(ulonglong2*)&Pl[ci * LDP + o * 8] = *(const ulonglong2*)&cp.u[0];
        *(ulonglong2*)&Al[ci * LDP + o * 8] = *(const ulonglong2*)&da.u[0];
    }

    // ---- pre-barrier: y2 (lane-local!) and x->bf16 A-operand -------------
    float y2 = 0.f;
    #pragma unroll
    for (int step = 0; step < 2; ++step)
        #pragma unroll
        for (int u = 0; u < 8; ++u) y2 = fmaf(xv[step][u], xv[step][u], y2);
    y2 += __shfl_xor(y2, 16, 64);
    y2 += __shfl_xor(y2, 32, 64);     // full ||x_row||^2, row = m16 group

    bf16x8 af[2];
    #pragma unroll
    for (int step = 0; step < 2; ++step) {
        union { unsigned short u[8]; bf16x8 v; } cv;
        #pragma unroll
        for (int u = 0; u < 8; ++u) cv.u[u] = f2bf(xv[step][u]);
        af[step] = cv.v;
    }

    __syncthreads();

    // ---- phase 2: per-t {frag reads, swapped MFMA, epilogue, f4 store} ---
    const float* sc0 = &scal[0][0];
    #pragma unroll
    for (int t = 0; t < 4; ++t) {
        const int off = (16 * t + m16) * LDP + quad * 8;
        bf16x8 bp0 = *(const bf16x8*)&Pl[off];
        bf16x8 ba0 = *(const bf16x8*)&Al[off];
        bf16x8 bp1 = *(const bf16x8*)&Pl[off + 32];
        bf16x8 ba1 = *(const bf16x8*)&Al[off + 32];

        f32x4 accP = (f32x4){0.f, 0.f, 0.f, 0.f};
        f32x4 accA = (f32x4){0.f, 0.f, 0.f, 0.f};
        // A = class frags, B = x frags  ->  D row = class, col = x-row
        accP = __builtin_amdgcn_mfma_f32_16x16x32_bf16(bp0, af[0], accP, 0, 0, 0);
        accA = __builtin_amdgcn_mfma_f32_16x16x32_bf16(ba0, af[0], accA, 0, 0, 0);
        accP = __builtin_amdgcn_mfma_f32_16x16x32_bf16(bp1, af[1], accP, 0, 0, 0);
        accA = __builtin_amdgcn_mfma_f32_16x16x32_bf16(ba1, af[1], accA, 0, 0, 0);

        const int sbase = 16 * t + quad * 4;        // class sub-index, %4==0
        const float4 x2v = *(const float4*)&scal[0][sbase];
        const float4 pav = *(const float4*)&scal[1][sbase];
        const float4 anv = *(const float4*)&scal[2][sbase];
        const float4 scv = *(const float4*)&scal[3][sbase];

        float lg[4];
        #pragma unroll
        for (int r = 0; r < 4; ++r) {
            const float x2 = (&x2v.x)[r], pa = (&pav.x)[r];
            const float an = (&anv.x)[r], sc = (&scv.x)[r];
            const float beta = 1.0f - KCURV * x2;
            const float xy = accP[r];
            const float xa = accA[r];
            float t1    = fmaf(2.0f * KCURV, xy, 1.0f);
            float den   = fmaf(KK * x2, y2, t1);              // mobius denom
            float alpha = fmaf(KCURV, y2, t1);
            float g     = fmaf(alpha, pa, beta * xa);
            float M     = fmaf(alpha * alpha, x2,
                          fmaf(2.0f * alpha * beta, xy, beta * beta * y2));
            // z = 2sqrt(k)·g·den / (an·(den² - k·M))  (single reciprocal)
            float dd    = fmaf(den, den, -KCURV * M);
            float z     = TWO_SQRT_K * g * den * __builtin_amdgcn_rcpf(an * dd);
            lg[r]       = sc * __logf(z + sqrtf(fmaf(z, z, 1.0f)));  // asinh
        }
        const int clb = cb + sbase;                 // global class base, %4==0
        if (gr < B && clb + 3 < C) {
            *(float4*)&out[(size_t)gr * C + clb] = *(const float4*)&lg[0];
        } else if (gr < B) {
            #pragma unroll
            for (int r = 0; r < 4; ++r)
                if (clb + r < C) out[(size_t)gr * C + clb + r] = lg[r];
        }
    }
}

extern "C" void kernel_launch(void* const* d_in, const int* in_sizes, int n_in,
                              void* d_out, int out_size, void* d_ws, size_t ws_size,
                              hipStream_t stream) {
    const float* x      = (const float*)d_in[0];
    const float* a_vals = (const float*)d_in[1];
    const float* p_vals = (const float*)d_in[2];
    const int B = in_sizes[0] / TD;
    const int C = in_sizes[1] / TD;
    const int rowBlocks = (B + 127) / 128;
    const int clsBlocks = (C + 63) / 64;

    dim3 grid(clsBlocks, rowBlocks);
    fused_mlr_kernel<<<grid, dim3(512), 0, stream>>>(
        x, a_vals, p_vals, (float*)d_out, B, C);
}